// Round 22
// baseline (46.962 us; speedup 1.0000x reference)
//
#include <hip/hip_runtime.h>
#include <math.h>

#define J   29
#define CH  3
#define JC  87            // J*CH
#define E0  56
#define B   256
#define T   1024
#define FRAMES (B*T)      // 262144
#define FPC 64            // frames per chunk (= lanes)
#define CPB 8             // chunks per block
#define NBLK (FRAMES/(FPC*CPB)) // 512 -> ~2 sequential blocks/CU
#define CHUNK_F4 1392     // float4s per chunk (22272 B)
#define BPB (T/(FPC*CPB)) // 2 partials per batch
#define SLOTS 4           // padded nnz per row (overflow beyond)
#define PROWS 32          // padded row count
#define MAXOV 96          // overflow capacity
#define WAVES 8
#define RPW 4             // rows per wave

// ---- prep: identical to R14/R18 (proven) ------------------------------------
__global__ void prep_kernel(const int* __restrict__ ei,
                            int2* __restrict__ pairs,
                            int*  __restrict__ ov_rp,
                            int2* __restrict__ ov_pairs)
{
    __shared__ float M[J * J];
    __shared__ float dinv[J];
    __shared__ int   cnt_ov[J];
    int tid = threadIdx.x;

    for (int i = tid; i < J * J; i += 64) M[i] = 0.f;
    if (tid < J) {
        int d = 1;
        for (int e = 0; e < E0; ++e) d += (ei[E0 + e] == tid) ? 1 : 0;
        dinv[tid] = rsqrtf((float)d);
    }
    __syncthreads();

    if (tid < J) {
        for (int e = 0; e < E0; ++e) {
            if (ei[E0 + e] == tid) {
                int s = ei[e];
                M[tid * J + s] += dinv[s] * dinv[tid];
            }
        }
        M[tid * J + tid] += dinv[tid] * dinv[tid];
        int c = 0;
        for (int i = 0; i < J; ++i) c += (M[tid * J + i] != 0.f) ? 1 : 0;
        cnt_ov[tid] = (c > SLOTS) ? (c - SLOTS) : 0;
    }
    __syncthreads();

    if (tid == 0) {
        int a = 0;
        for (int j = 0; j < J; ++j) { ov_rp[j] = a; a += cnt_ov[j]; }
        for (int j = J; j <= 32; ++j) ov_rp[j] = a;
    }
    __syncthreads();

    if (tid < PROWS) {
        int2 zero; zero.x = 0; zero.y = 0;
        if (tid < J) {
            int s = 0, p = ov_rp[tid];
            for (int i = 0; i < J; ++i) {
                float v = M[tid * J + i];
                if (v != 0.f) {
                    if (s < SLOTS) {
                        int2 pr; pr.x = i * 12; pr.y = __float_as_int(v);
                        pairs[tid * SLOTS + s] = pr;
                    } else {
                        int2 pr; pr.x = (tid << 16) | (i * 12); pr.y = __float_as_int(v);
                        ov_pairs[p++] = pr;
                    }
                    ++s;
                }
            }
            for (; s < SLOTS; ++s) pairs[tid * SLOTS + s] = zero;
        } else {
            for (int s = 0; s < SLOTS; ++s) pairs[tid * SLOTS + s] = zero;
        }
    }
    __syncthreads();
    if (tid == 0) {
        int a = ov_rp[J];
        for (int i = a; i < MAXOV; ++i) { int2 pr; pr.x = 0; pr.y = 0; ov_pairs[i] = pr; }
    }
}

// ---- main: depth-3 reg pipeline, 4-buffer LDS ring, 256-VGPR budget --------
__global__ __launch_bounds__(512)
__attribute__((amdgpu_waves_per_eu(2, 2)))   // cap 2 waves/EU -> 256 VGPR budget
void gcn_main(const float* __restrict__ x,
              const float* __restrict__ Wp,
              const float* __restrict__ bp,
              const int2* __restrict__ pairs,
              const int*  __restrict__ ov_rp,
              const int2* __restrict__ ov_pairs,
              float* __restrict__ partials) {
    __shared__ float4 xs4[4][CHUNK_F4];   // 4 x 22272 B ring (89 KB)
    __shared__ int2   s_ov[MAXOV];

    int tid  = threadIdx.x;
    int lane = tid & 63;
    int wv   = tid >> 6;
    int rowbase = __builtin_amdgcn_readfirstlane(wv * RPW);

    float sW[9], sb[CH];
#pragma unroll
    for (int i = 0; i < 9; ++i) sW[i] = Wp[i];
#pragma unroll
    for (int i = 0; i < CH; ++i) sb[i] = bp[i];
    int ov0 = ov_rp[rowbase], ov1 = ov_rp[rowbase + RPW];
    if (tid < MAXOV) s_ov[tid] = ov_pairs[tid];

    const float4* src4 = (const float4*)x + (size_t)blockIdx.x * (CPB * CHUNK_F4);
    int i2 = 1024 + tid; if (i2 > CHUNK_F4 - 1) i2 = CHUNK_F4 - 1;

    float acc[RPW][CH];
#pragma unroll
    for (int r = 0; r < RPW; ++r)
#pragma unroll
        for (int c = 0; c < CH; ++c) acc[r][c] = 0.f;

#define LOADSET(S, CK)                                                        \
    {                                                                         \
        const float4* sp_ = src4 + (CK) * CHUNK_F4;                           \
        S##0 = sp_[tid]; S##1 = sp_[512 + tid]; S##2 = sp_[i2];               \
    }
#define WRITESET(S, BUF)                                                      \
    xs4[BUF][tid] = S##0; xs4[BUF][512 + tid] = S##1; xs4[BUF][i2] = S##2;

#define RAW_BARRIER()                                                         \
    asm volatile("s_waitcnt lgkmcnt(0)" ::: "memory");                        \
    __builtin_amdgcn_s_barrier();                                             \
    __builtin_amdgcn_sched_barrier(0);                                        \
    asm volatile("" ::: "memory");

#define COMPUTE_CHUNK(BUF)                                                    \
    {                                                                         \
        const char* xf = (const char*)xs4[BUF] + lane * 348;                  \
        float y[RPW][CH];                                                     \
        _Pragma("unroll")                                                     \
        for (int R = 0; R < RPW; ++R) {                                       \
            float a0 = 0.f, a1 = 0.f, a2 = 0.f;                               \
            _Pragma("unroll")                                                 \
            for (int sl = 0; sl < SLOTS; ++sl) {                              \
                int2 pr = pairs[(rowbase + R) * SLOTS + sl];                  \
                float v = __int_as_float(pr.y);                               \
                const float* q = (const float*)(xf + pr.x);                   \
                a0 += v * q[0]; a1 += v * q[1]; a2 += v * q[2];               \
            }                                                                 \
            y[R][0] = a0; y[R][1] = a1; y[R][2] = a2;                         \
        }                                                                     \
        for (int e = ov0; e < ov1; ++e) {                                     \
            int2 pr = s_ov[e];                                                \
            int row = pr.x >> 16; int off = pr.x & 0xFFFF;                    \
            float v = __int_as_float(pr.y);                                   \
            const float* q = (const float*)(xf + off);                        \
            float d0 = v * q[0], d1 = v * q[1], d2 = v * q[2];                \
            _Pragma("unroll")                                                 \
            for (int R = 0; R < RPW; ++R)                                     \
                if (row == rowbase + R) { y[R][0] += d0; y[R][1] += d1; y[R][2] += d2; } \
        }                                                                     \
        _Pragma("unroll")                                                     \
        for (int R = 0; R < RPW; ++R)                                         \
            _Pragma("unroll")                                                 \
            for (int ch = 0; ch < CH; ++ch) {                                 \
                float t = y[R][0] * sW[0 * CH + ch]                           \
                        + y[R][1] * sW[1 * CH + ch]                           \
                        + y[R][2] * sW[2 * CH + ch]                           \
                        + sb[ch];                                             \
                acc[R][ch] += fmaxf(t, 0.f);                                  \
            }                                                                 \
    }

    // named pipeline registers: 3 sets x 3 float4 = 36 VGPR
    float4 SA0, SA1, SA2, SB0, SB1, SB2, SC0, SC1, SC2;

    // prologue: 3 chunks in flight
    LOADSET(SA, 0)
    LOADSET(SB, 1)
    LOADSET(SC, 2)

    // straight-line: iter c -> set {A,B,C}[c%3], buffer c%4, prefetch c+3
    WRITESET(SA, 0)  LOADSET(SA, 3)  RAW_BARRIER()  COMPUTE_CHUNK(0)
    WRITESET(SB, 1)  LOADSET(SB, 4)  RAW_BARRIER()  COMPUTE_CHUNK(1)
    WRITESET(SC, 2)  LOADSET(SC, 5)  RAW_BARRIER()  COMPUTE_CHUNK(2)
    WRITESET(SA, 3)  LOADSET(SA, 6)  RAW_BARRIER()  COMPUTE_CHUNK(3)
    WRITESET(SB, 0)  LOADSET(SB, 7)  RAW_BARRIER()  COMPUTE_CHUNK(0)
    WRITESET(SC, 1)                  RAW_BARRIER()  COMPUTE_CHUNK(1)
    WRITESET(SA, 2)                  RAW_BARRIER()  COMPUTE_CHUNK(2)
    WRITESET(SB, 3)                  RAW_BARRIER()  COMPUTE_CHUNK(3)

    // ---- epilogue: transposed LDS write + 87-thread column reduce ----------
    __syncthreads();   // loop done; nothing useful in flight
    float* red = (float*)xs4[0];
#pragma unroll
    for (int R = 0; R < RPW; ++R) {
        int j = rowbase + R;
        if (j < J) {
#pragma unroll
            for (int ch = 0; ch < CH; ++ch)
                red[lane * JC + j * CH + ch] = acc[R][ch];
        }
    }
    __syncthreads();
    if (tid < JC) {
        float a = 0.f;
#pragma unroll
        for (int L = 0; L < FPC; ++L) a += red[L * JC + tid];
        partials[(size_t)blockIdx.x * JC + tid] = a;
    }
}

// ---- finalize: identical to R18 ---------------------------------------------
__global__ void finalize_kernel(const float* __restrict__ partials,
                                const float* __restrict__ fcW,
                                const float* __restrict__ fcb,
                                float* __restrict__ out) {
    __shared__ float h[JC];
    int b = blockIdx.x, tid = threadIdx.x;
    if (tid < JC) {
        float a = 0.f;
#pragma unroll
        for (int p = 0; p < BPB; ++p)
            a += partials[(size_t)(b * BPB + p) * JC + tid];
        a *= (1.0f / (float)T);
        h[tid] = a;
        out[(size_t)b * JC + tid] = a;
    }
    __syncthreads();
    if (tid < 2) {
        float a = fcb[tid];
        for (int r = 0; r < JC; ++r) a += h[r] * fcW[r * 2 + tid];
        out[(size_t)B * JC + b * 2 + tid] = 1.0f / (1.0f + expf(-a));
    }
}

extern "C" void kernel_launch(void* const* d_in, const int* in_sizes, int n_in,
                              void* d_out, int out_size, void* d_ws, size_t ws_size,
                              hipStream_t stream) {
    const float* x   = (const float*)d_in[0];
    const int*   ei  = (const int*)d_in[1];
    const float* W   = (const float*)d_in[4];
    const float* bb  = (const float*)d_in[5];
    const float* fcW = (const float*)d_in[6];
    const float* fcb = (const float*)d_in[7];

    char* ws = (char*)d_ws;
    int2* pairs    = (int2*)ws;
    int2* ov_pairs = pairs + PROWS * SLOTS;
    int*  ov_rp    = (int*)(ov_pairs + MAXOV);
    float* partials = (float*)(ws + 4096);            // 512*87 floats

    prep_kernel<<<1, 64, 0, stream>>>(ei, pairs, ov_rp, ov_pairs);
    gcn_main<<<NBLK, WAVES * 64, 0, stream>>>(x, W, bb, pairs, ov_rp, ov_pairs, partials);
    finalize_kernel<<<B, 128, 0, stream>>>(partials, fcW, fcb, (float*)d_out);
}

// Round 23
// 43.170 us; speedup vs baseline: 1.0878x; 1.0878x over previous
//
#include <hip/hip_runtime.h>
#include <math.h>

#define J   29
#define CH  3
#define JC  87            // J*CH
#define E0  56
#define B   256
#define T   1024
#define FRAMES (B*T)      // 262144
#define FPC 64            // frames per chunk (= lanes)
#define CPB 8             // chunks per block
#define NBLK (FRAMES/(FPC*CPB)) // 512 -> exactly 2 blocks/CU, one generation
#define CHUNK_F4 1392     // float4s per chunk (22272 B)
#define BPB (T/(FPC*CPB)) // 2 partials per batch
#define SLOTS 4           // padded nnz per row (overflow beyond)
#define PROWS 32          // padded row count
#define MAXOV 96          // overflow capacity
#define WAVES 8
#define RPW 4             // rows per wave

// ---- prep: identical to R14/R18 (proven) ------------------------------------
__global__ void prep_kernel(const int* __restrict__ ei,
                            int2* __restrict__ pairs,
                            int*  __restrict__ ov_rp,
                            int2* __restrict__ ov_pairs)
{
    __shared__ float M[J * J];
    __shared__ float dinv[J];
    __shared__ int   cnt_ov[J];
    int tid = threadIdx.x;

    for (int i = tid; i < J * J; i += 64) M[i] = 0.f;
    if (tid < J) {
        int d = 1;
        for (int e = 0; e < E0; ++e) d += (ei[E0 + e] == tid) ? 1 : 0;
        dinv[tid] = rsqrtf((float)d);
    }
    __syncthreads();

    if (tid < J) {
        for (int e = 0; e < E0; ++e) {
            if (ei[E0 + e] == tid) {
                int s = ei[e];
                M[tid * J + s] += dinv[s] * dinv[tid];
            }
        }
        M[tid * J + tid] += dinv[tid] * dinv[tid];
        int c = 0;
        for (int i = 0; i < J; ++i) c += (M[tid * J + i] != 0.f) ? 1 : 0;
        cnt_ov[tid] = (c > SLOTS) ? (c - SLOTS) : 0;
    }
    __syncthreads();

    if (tid == 0) {
        int a = 0;
        for (int j = 0; j < J; ++j) { ov_rp[j] = a; a += cnt_ov[j]; }
        for (int j = J; j <= 32; ++j) ov_rp[j] = a;
    }
    __syncthreads();

    if (tid < PROWS) {
        int2 zero; zero.x = 0; zero.y = 0;
        if (tid < J) {
            int s = 0, p = ov_rp[tid];
            for (int i = 0; i < J; ++i) {
                float v = M[tid * J + i];
                if (v != 0.f) {
                    if (s < SLOTS) {
                        int2 pr; pr.x = i * 12; pr.y = __float_as_int(v);
                        pairs[tid * SLOTS + s] = pr;
                    } else {
                        int2 pr; pr.x = (tid << 16) | (i * 12); pr.y = __float_as_int(v);
                        ov_pairs[p++] = pr;
                    }
                    ++s;
                }
            }
            for (; s < SLOTS; ++s) pairs[tid * SLOTS + s] = zero;
        } else {
            for (int s = 0; s < SLOTS; ++s) pairs[tid * SLOTS + s] = zero;
        }
    }
    __syncthreads();
    if (tid == 0) {
        int a = ov_rp[J];
        for (int i = a; i < MAXOV; ++i) { int2 pr; pr.x = 0; pr.y = 0; ov_pairs[i] = pr; }
    }
}

// ---- main: ring-3 LDS, depth-3 in flight, 2 blocks/CU (16 waves) -----------
__global__ __launch_bounds__(512)
__attribute__((amdgpu_waves_per_eu(4, 4)))   // 4 waves/EU -> 128-VGPR budget
void gcn_main(const float* __restrict__ x,
              const float* __restrict__ Wp,
              const float* __restrict__ bp,
              const int2* __restrict__ pairs,
              const int*  __restrict__ ov_rp,
              const int2* __restrict__ ov_pairs,
              float* __restrict__ partials) {
    __shared__ float4 xs4[3][CHUNK_F4];   // 3 x 22272 B ring (67 KB) -> 2 blocks/CU
    __shared__ int2   s_ov[MAXOV];

    int tid  = threadIdx.x;
    int lane = tid & 63;
    int wv   = tid >> 6;
    int rowbase = __builtin_amdgcn_readfirstlane(wv * RPW);

    float sW[9], sb[CH];
#pragma unroll
    for (int i = 0; i < 9; ++i) sW[i] = Wp[i];
#pragma unroll
    for (int i = 0; i < CH; ++i) sb[i] = bp[i];
    int ov0 = ov_rp[rowbase], ov1 = ov_rp[rowbase + RPW];
    if (tid < MAXOV) s_ov[tid] = ov_pairs[tid];

    const float4* src4 = (const float4*)x + (size_t)blockIdx.x * (CPB * CHUNK_F4);
    int i2 = 1024 + tid; if (i2 > CHUNK_F4 - 1) i2 = CHUNK_F4 - 1;

    float acc[RPW][CH];
#pragma unroll
    for (int r = 0; r < RPW; ++r)
#pragma unroll
        for (int c = 0; c < CH; ++c) acc[r][c] = 0.f;

#define LOADSET(S, CK)                                                        \
    {                                                                         \
        const float4* sp_ = src4 + (CK) * CHUNK_F4;                           \
        S##0 = sp_[tid]; S##1 = sp_[512 + tid]; S##2 = sp_[i2];               \
    }
#define WRITESET(S, BUF)                                                      \
    xs4[BUF][tid] = S##0; xs4[BUF][512 + tid] = S##1; xs4[BUF][i2] = S##2;

// raw barrier: flush LDS writes only; vmem prefetches stay in flight
#define RAW_BARRIER()                                                         \
    asm volatile("s_waitcnt lgkmcnt(0)" ::: "memory");                        \
    __builtin_amdgcn_s_barrier();                                             \
    __builtin_amdgcn_sched_barrier(0);                                        \
    asm volatile("" ::: "memory");

#define COMPUTE_CHUNK(BUF)                                                    \
    {                                                                         \
        const char* xf = (const char*)xs4[BUF] + lane * 348;                  \
        float y[RPW][CH];                                                     \
        _Pragma("unroll")                                                     \
        for (int R = 0; R < RPW; ++R) {                                       \
            float a0 = 0.f, a1 = 0.f, a2 = 0.f;                               \
            _Pragma("unroll")                                                 \
            for (int sl = 0; sl < SLOTS; ++sl) {                              \
                int2 pr = pairs[(rowbase + R) * SLOTS + sl];                  \
                float v = __int_as_float(pr.y);                               \
                const float* q = (const float*)(xf + pr.x);                   \
                a0 += v * q[0]; a1 += v * q[1]; a2 += v * q[2];               \
            }                                                                 \
            y[R][0] = a0; y[R][1] = a1; y[R][2] = a2;                         \
        }                                                                     \
        for (int e = ov0; e < ov1; ++e) {                                     \
            int2 pr = s_ov[e];                                                \
            int row = pr.x >> 16; int off = pr.x & 0xFFFF;                    \
            float v = __int_as_float(pr.y);                                   \
            const float* q = (const float*)(xf + off);                        \
            float d0 = v * q[0], d1 = v * q[1], d2 = v * q[2];                \
            _Pragma("unroll")                                                 \
            for (int R = 0; R < RPW; ++R)                                     \
                if (row == rowbase + R) { y[R][0] += d0; y[R][1] += d1; y[R][2] += d2; } \
        }                                                                     \
        _Pragma("unroll")                                                     \
        for (int R = 0; R < RPW; ++R)                                         \
            _Pragma("unroll")                                                 \
            for (int ch = 0; ch < CH; ++ch) {                                 \
                float t = y[R][0] * sW[0 * CH + ch]                           \
                        + y[R][1] * sW[1 * CH + ch]                           \
                        + y[R][2] * sW[2 * CH + ch]                           \
                        + sb[ch];                                             \
                acc[R][ch] += fmaxf(t, 0.f);                                  \
            }                                                                 \
    }

    // named pipeline registers: 3 sets x 3 float4 = 36 VGPR
    float4 SA0, SA1, SA2, SB0, SB1, SB2, SC0, SC1, SC2;

    // prologue: 3 chunks in flight before any wait
    LOADSET(SA, 0)
    LOADSET(SB, 1)
    LOADSET(SC, 2)

    // iter c: WRITESET waits ONLY set c's loads (auto counted vmcnt, 6 newer
    // loads stay in flight); then issue c+3; barrier; compute.
    WRITESET(SA, 0)  LOADSET(SA, 3)  RAW_BARRIER()  COMPUTE_CHUNK(0)
    WRITESET(SB, 1)  LOADSET(SB, 4)  RAW_BARRIER()  COMPUTE_CHUNK(1)
    WRITESET(SC, 2)  LOADSET(SC, 5)  RAW_BARRIER()  COMPUTE_CHUNK(2)
    WRITESET(SA, 0)  LOADSET(SA, 6)  RAW_BARRIER()  COMPUTE_CHUNK(0)
    WRITESET(SB, 1)  LOADSET(SB, 7)  RAW_BARRIER()  COMPUTE_CHUNK(1)
    WRITESET(SC, 2)                  RAW_BARRIER()  COMPUTE_CHUNK(2)
    WRITESET(SA, 0)                  RAW_BARRIER()  COMPUTE_CHUNK(0)
    WRITESET(SB, 1)                  RAW_BARRIER()  COMPUTE_CHUNK(1)

    // ---- epilogue: transposed LDS write + 87-thread column reduce ----------
    __syncthreads();   // loop done; nothing useful in flight
    float* red = (float*)xs4[0];
#pragma unroll
    for (int R = 0; R < RPW; ++R) {
        int j = rowbase + R;
        if (j < J) {
#pragma unroll
            for (int ch = 0; ch < CH; ++ch)
                red[lane * JC + j * CH + ch] = acc[R][ch];
        }
    }
    __syncthreads();
    if (tid < JC) {
        float a = 0.f;
#pragma unroll
        for (int L = 0; L < FPC; ++L) a += red[L * JC + tid];
        partials[(size_t)blockIdx.x * JC + tid] = a;
    }
}

// ---- finalize: identical to R18 ---------------------------------------------
__global__ void finalize_kernel(const float* __restrict__ partials,
                                const float* __restrict__ fcW,
                                const float* __restrict__ fcb,
                                float* __restrict__ out) {
    __shared__ float h[JC];
    int b = blockIdx.x, tid = threadIdx.x;
    if (tid < JC) {
        float a = 0.f;
#pragma unroll
        for (int p = 0; p < BPB; ++p)
            a += partials[(size_t)(b * BPB + p) * JC + tid];
        a *= (1.0f / (float)T);
        h[tid] = a;
        out[(size_t)b * JC + tid] = a;
    }
    __syncthreads();
    if (tid < 2) {
        float a = fcb[tid];
        for (int r = 0; r < JC; ++r) a += h[r] * fcW[r * 2 + tid];
        out[(size_t)B * JC + b * 2 + tid] = 1.0f / (1.0f + expf(-a));
    }
}

extern "C" void kernel_launch(void* const* d_in, const int* in_sizes, int n_in,
                              void* d_out, int out_size, void* d_ws, size_t ws_size,
                              hipStream_t stream) {
    const float* x   = (const float*)d_in[0];
    const int*   ei  = (const int*)d_in[1];
    const float* W   = (const float*)d_in[4];
    const float* bb  = (const float*)d_in[5];
    const float* fcW = (const float*)d_in[6];
    const float* fcb = (const float*)d_in[7];

    char* ws = (char*)d_ws;
    int2* pairs    = (int2*)ws;
    int2* ov_pairs = pairs + PROWS * SLOTS;
    int*  ov_rp    = (int*)(ov_pairs + MAXOV);
    float* partials = (float*)(ws + 4096);            // 512*87 floats

    prep_kernel<<<1, 64, 0, stream>>>(ei, pairs, ov_rp, ov_pairs);
    gcn_main<<<NBLK, WAVES * 64, 0, stream>>>(x, W, bb, pairs, ov_rp, ov_pairs, partials);
    finalize_kernel<<<B, 128, 0, stream>>>(partials, fcW, fcb, (float*)d_out);
}